// Round 7
// baseline (54.548 us; speedup 1.0000x reference)
//
#include <hip/hip_runtime.h>

typedef __attribute__((ext_vector_type(8))) short bf16x8;
typedef __attribute__((ext_vector_type(4))) float f32x4;

#define HW_   252
#define PLANE 63504            // 252*252
#define NCH   32
#define PADW  262              // materialized padded extent
#define PROW  (PADW * NCH)     // elems per padded row = 8384
#define PIMG  ((size_t)PADW * PROW)
#define XPAD_ELEMS ((size_t)8 * PIMG)
#define WP_OFF_BYTES (XPAD_ELEMS * 2)
#define WS_NEED (WP_OFF_BYTES + 25600u * 2u)

__device__ __forceinline__ unsigned short f2bf(float f) {
    unsigned u = __builtin_bit_cast(unsigned, f);
    u += 0x7FFFu + ((u >> 16) & 1u);   // round-to-nearest-even
    return (unsigned short)(u >> 16);
}

// padded coord p (0..261) -> source index: circular mod 256, then reflect(p-2)
__device__ __forceinline__ int refl(int p) {
    int t = (p & 255) - 2;
    t = t < 0 ? -t : t;
    return t > 251 ? 502 - t : t;
}

// Fused pad+transpose+weight-pack (unchanged — near its BW floor).
__global__ __launch_bounds__(256) void pad_pack(
    const float* __restrict__ x, unsigned short* __restrict__ xp,
    const float* __restrict__ w, unsigned short* __restrict__ wp)
{
    const int bid = blockIdx.x;
    const int tid = threadIdx.x;

    if (bid >= 8 * PADW) {                 // ---- weight pack ----
        int e = (bid - 8 * PADW) * 256 + tid;   // [25][32][32]
        int ci = e & 31;
        int o  = (e >> 5) & 31;
        int t  = e >> 10;
        int da = t / 5, db = t - da * 5;
        wp[e] = f2bf(w[((o * 32 + ci) * 5 + (4 - da)) * 5 + (4 - db)]);
        return;
    }

    __shared__ unsigned short s[32][260];  // [ci][src col]

    const int b  = bid / PADW;
    const int r  = bid - b * PADW;
    const int mr = refl(r);
    const float* src0 = x + (size_t)b * NCH * PLANE + (size_t)mr * HW_;

    {
        const int ci   = tid >> 3;
        const int part = tid & 7;
        const float* sp = src0 + (size_t)ci * PLANE;
        #pragma unroll
        for (int c4 = 0; c4 < 8; ++c4) {
            int col = part * 32 + c4 * 4;
            if (col < HW_) {
                float4 v = *reinterpret_cast<const float4*>(sp + col);
                s[ci][col + 0] = f2bf(v.x);
                s[ci][col + 1] = f2bf(v.y);
                s[ci][col + 2] = f2bf(v.z);
                s[ci][col + 3] = f2bf(v.w);
            }
        }
    }
    __syncthreads();

    unsigned short* dst0 = xp + (size_t)b * PIMG + (size_t)r * PROW;
    const int cpart = tid >> 2;
    const int g     = tid & 3;
    #pragma unroll
    for (int cb = 0; cb < PADW; cb += 64) {
        int c = cb + cpart;
        if (c < PADW) {
            int mc = refl(c);
            unsigned short pk[8];
            #pragma unroll
            for (int q = 0; q < 8; ++q) pk[q] = s[g * 8 + q][mc];
            *reinterpret_cast<uint4*>(dst0 + (size_t)c * NCH + g * 8) =
                *reinterpret_cast<const uint4*>(pk);
        }
    }
}

// Conv v6: 28 rows x 16 cols per block, 4 waves x 7 rows, 40 KB patch.
// Changes vs v5: (1) A-frag double-buffer prefetch — db0 weights issued
// BEFORE the barrier (overlap patch DMA), db+1 prefetched under db's MFMAs;
// (2) launch_bounds(256,3): VGPR cap 170 (abuf 80 + acc 56 + misc — no spill).
__global__ __launch_bounds__(256, 3) void conv_mfma_v6(
    const unsigned short* __restrict__ xp,
    const unsigned short* __restrict__ wp,
    float* __restrict__ out)
{
    __shared__ unsigned short xl[32 * 20 * 32];   // 40960 B, linear [pr][col][ci]

    const int tid  = threadIdx.x;
    const int orig = blockIdx.x;                  // 1152 blocks = 8 XCD * 144
    const int b    = orig & 7;                    // XCD-bijective: image b per XCD
    const int idx  = orig >> 3;                   // 0..143
    const int rt   = idx >> 4;                    // 0..8
    const int ct   = idx & 15;                    // 0..15
    const int i0 = rt * 28, j0 = ct * 16;

    const int lane = tid & 63;
    const int wid  = tid >> 6;

    const int lm   = lane & 15;    // o-within-16 (A) / pixel col (B,D)
    const int lg   = lane >> 4;    // k-group
    const char* wb = reinterpret_cast<const char*>(wp);
    const int afix = (lm << 6) + (lg << 4);

    // ---- stage 32x20x32 bf16 patch (2560 x 16B units, exactly 10 iters) ----
    {
        const char* gb = (const char*)(xp +
            ((size_t)b * PIMG + (size_t)(i0 + 1) * PROW + (size_t)(j0 + 1) * NCH));
        #pragma unroll
        for (int it = 0; it < 10; ++it) {
            int unit = it * 256 + tid;
            int pr   = unit / 80;                 // 20 cols * 64B = 80 units/row
            int u    = unit - pr * 80;
            const char* src = gb + (size_t)pr * (PROW * 2) + u * 16;
            char* ldst = ((char*)xl) + (it * 4096 + wid * 1024);  // wave-uniform
            __builtin_amdgcn_global_load_lds(
                (const __attribute__((address_space(1))) void*)src,
                (__attribute__((address_space(3))) void*)ldst,
                16, 0, 0);
        }
    }

    // A-frag double buffer. db=0 loads issued pre-barrier: overlap the DMA.
    bf16x8 abuf[2][5][2];
    #pragma unroll
    for (int da = 0; da < 5; ++da) {
        const char* ap = wb + ((da * 5 + 0) << 11) + afix;
        abuf[0][da][0] = *reinterpret_cast<const bf16x8*>(ap);
        abuf[0][da][1] = *reinterpret_cast<const bf16x8*>(ap + 1024);
    }

    __syncthreads();

    const int rowb = wid * 7;      // wave's first local output row
    const char* xlb = reinterpret_cast<const char*>(xl);
    const int j     = j0 + lm;

    f32x4 acc[7][2];
    #pragma unroll
    for (int r = 0; r < 7; ++r) {
        acc[r][0] = (f32x4){0.f, 0.f, 0.f, 0.f};
        acc[r][1] = (f32x4){0.f, 0.f, 0.f, 0.f};
    }

    #pragma unroll
    for (int db = 0; db < 5; ++db) {
        const int cur = db & 1;        // compile-time after full unroll
        const int nxt = cur ^ 1;

        // prefetch next db's A-frags; latency hides under this db's MFMAs
        if (db < 4) {
            #pragma unroll
            for (int da = 0; da < 5; ++da) {
                const char* ap = wb + ((da * 5 + db + 1) << 11) + afix;
                abuf[nxt][da][0] = *reinterpret_cast<const bf16x8*>(ap);
                abuf[nxt][da][1] = *reinterpret_cast<const bf16x8*>(ap + 1024);
            }
        }

        #pragma unroll
        for (int l = 0; l < 11; ++l) {
            // patch row rowb+l, cols lm+db: contiguous 1KB per wave, conflict-free
            bf16x8 bf = *reinterpret_cast<const bf16x8*>(
                xlb + (rowb + l) * 1280 + ((lm + db) << 6) + (lg << 4));
            #pragma unroll
            for (int da = 0; da < 5; ++da) {
                const int r = l - da;
                if (r >= 0 && r < 7) {
                    acc[r][0] = __builtin_amdgcn_mfma_f32_16x16x32_bf16(
                        abuf[cur][da][0], bf, acc[r][0], 0, 0, 0);
                    acc[r][1] = __builtin_amdgcn_mfma_f32_16x16x32_bf16(
                        abuf[cur][da][1], bf, acc[r][1], 0, 0, 0);
                }
            }
        }
    }

    // store: o = mt*16 + lg*4 + q, col = lm (rows always in-bounds; 252=9*28)
    #pragma unroll
    for (int r = 0; r < 7; ++r) {
        const int i = i0 + rowb + r;
        if (j < HW_) {
            #pragma unroll
            for (int mt = 0; mt < 2; ++mt) {
                size_t rowoff = ((size_t)(b * NCH + mt * 16 + lg * 4)) * PLANE
                              + (size_t)i * HW_ + j;
                #pragma unroll
                for (int q = 0; q < 4; ++q)
                    out[rowoff + (size_t)q * PLANE] = acc[r][mt][q];
            }
        }
    }
}

// ---------------- fallback (ws too small): R2-style single kernel ----------------
__global__ __launch_bounds__(256) void conv_mfma_fb(
    const float* __restrict__ x,
    const float* __restrict__ w_raw,
    float* __restrict__ out)
{
    __shared__ unsigned short xl[12800];
    __shared__ unsigned short wl[25600];
    __shared__ int rmap[20], cmap[20];

    const int tid = threadIdx.x;
    const int bid = blockIdx.x;
    const int b  = bid >> 8;
    const int rt = (bid >> 4) & 15;
    const int ct = bid & 15;
    const int i0 = rt * 16, j0 = ct * 16;

    if (tid < 40) {
        int k    = tid < 20 ? tid : tid - 20;
        int base = tid < 20 ? i0  : j0;
        int r = (base + 1 + k) & 255;
        int t = r - 2;
        int m = t < 0 ? -t : (t > 251 ? 502 - t : t);
        if (tid < 20) rmap[k] = m; else cmap[k] = m;
    }
    for (int e = tid; e < 25600; e += 256) {
        int o   = e / 800;
        int rem = e - o * 800;
        int ci  = rem / 25;
        int kd  = rem - ci * 25;
        wl[(24 - kd) * 1024 + o * 32 + ci] = f2bf(w_raw[e]);
    }
    __syncthreads();

    for (int task = tid; task < 1600; task += 256) {
        int col = task % 20;
        int g   = (task / 20) & 3;
        int row = task / 80;
        const float* src = x + (size_t)(b * NCH + g * 8) * PLANE
                             + (size_t)rmap[row] * HW_ + cmap[col];
        unsigned short pk[8];
        #pragma unroll
        for (int q = 0; q < 8; ++q) pk[q] = f2bf(src[q * PLANE]);
        int off = ((row * 20 + col) << 6) + ((g ^ (col & 3)) << 4);
        *reinterpret_cast<uint4*>(reinterpret_cast<char*>(xl) + off)
            = *reinterpret_cast<const uint4*>(pk);
    }
    __syncthreads();

    const int lane  = tid & 63;
    const int wid   = tid >> 6;
    const int lm    = lane & 15;
    const int lg    = lane >> 4;
    const int rbase = wid * 4;

    f32x4 acc[4][2];
    #pragma unroll
    for (int rr = 0; rr < 4; ++rr) {
        acc[rr][0] = (f32x4){0.f, 0.f, 0.f, 0.f};
        acc[rr][1] = (f32x4){0.f, 0.f, 0.f, 0.f};
    }

    const char* wbase = (const char*)wl;
    const int afix = (lm << 6) + (lg << 4);
    const char* xlb = reinterpret_cast<const char*>(xl);

    #pragma unroll
    for (int da = 0; da < 5; ++da) {
        #pragma unroll
        for (int db = 0; db < 5; ++db) {
            const int t = da * 5 + db;
            bf16x8 a0 = *reinterpret_cast<const bf16x8*>(wbase + (t << 11) + afix);
            bf16x8 a1 = *reinterpret_cast<const bf16x8*>(wbase + (t << 11) + 1024 + afix);
            const int col  = lm + db;
            const int coff = (col << 6) + ((lg ^ (col & 3)) << 4);
            #pragma unroll
            for (int rr = 0; rr < 4; ++rr) {
                const int row = rbase + rr + da;
                bf16x8 bf = *reinterpret_cast<const bf16x8*>(xlb + row * 1280 + coff);
                acc[rr][0] = __builtin_amdgcn_mfma_f32_16x16x32_bf16(a0, bf, acc[rr][0], 0, 0, 0);
                acc[rr][1] = __builtin_amdgcn_mfma_f32_16x16x32_bf16(a1, bf, acc[rr][1], 0, 0, 0);
            }
        }
    }

    const int j = j0 + lm;
    #pragma unroll
    for (int rr = 0; rr < 4; ++rr) {
        const int i = i0 + rbase + rr;
        if (i < HW_ && j < HW_) {
            size_t rowoff = (size_t)(b * NCH) * PLANE + (size_t)i * HW_ + j;
            #pragma unroll
            for (int mt = 0; mt < 2; ++mt)
                #pragma unroll
                for (int q = 0; q < 4; ++q) {
                    int o = mt * 16 + lg * 4 + q;
                    out[rowoff + (size_t)o * PLANE] = acc[rr][mt][q];
                }
        }
    }
}

extern "C" void kernel_launch(void* const* d_in, const int* in_sizes, int n_in,
                              void* d_out, int out_size, void* d_ws, size_t ws_size,
                              hipStream_t stream) {
    const float* x = (const float*)d_in[0];
    const float* w = (const float*)d_in[1];
    float* out = (float*)d_out;

    if (ws_size >= WS_NEED) {
        unsigned short* xpad = (unsigned short*)d_ws;
        unsigned short* wp   = (unsigned short*)((char*)d_ws + WP_OFF_BYTES);
        hipLaunchKernelGGL(pad_pack, dim3(8 * PADW + 100), dim3(256), 0, stream,
                           x, xpad, w, wp);
        hipLaunchKernelGGL(conv_mfma_v6, dim3(1152), dim3(256), 0, stream,
                           (const unsigned short*)xpad, (const unsigned short*)wp, out);
    } else {
        hipLaunchKernelGGL(conv_mfma_fb, dim3(2048), dim3(256), 0, stream, x, w, out);
    }
}

// Round 8
// 46.645 us; speedup vs baseline: 1.1694x; 1.1694x over previous
//
#include <hip/hip_runtime.h>
#include <hip/hip_bf16.h>

typedef __attribute__((ext_vector_type(8))) short bf16x8;
typedef __attribute__((ext_vector_type(4))) float f32x4;

#define HW_   252
#define PLANE 63504            // 252*252
#define NCH   32
#define WS_NEED (25600u * 2u)  // packed weights only

__device__ __forceinline__ unsigned short f2bf(float f) {
    unsigned u = __builtin_bit_cast(unsigned, f);
    u += 0x7FFFu + ((u >> 16) & 1u);   // round-to-nearest-even
    return (unsigned short)(u >> 16);
}

// wp[t][o][ci] = bf16(w[o][ci][4-da][4-db]), t = da*5+db
__global__ void pack_w_kernel(const float* __restrict__ w, unsigned short* __restrict__ wp) {
    int e = blockIdx.x * 256 + threadIdx.x;   // [25][32][32]
    if (e >= 25600) return;
    int ci = e & 31;
    int o  = (e >> 5) & 31;
    int t  = e >> 10;
    int da = t / 5, db = t - da * 5;
    wp[e] = f2bf(w[((o * 32 + ci) * 5 + (4 - da)) * 5 + (4 - db)]);
}

// Fused conv: reads NCHW fp32 x directly (reflect+circular pad on the fly),
// stages 32x20x32 bf16 patch in LDS, 28x16 output tile, shift-reuse MFMA loop.
// Staging: task=(pr*20+col)*4+g -> 8 plane-strided loads + cvt + 1 linear
// ds_write_b128 (consecutive lanes -> contiguous 1KB: conflict-free).
__global__ __launch_bounds__(256, 3) void conv_fused(
    const float* __restrict__ x,
    const unsigned short* __restrict__ wp,
    float* __restrict__ out)
{
    __shared__ unsigned short xl[32 * 20 * 32];   // 40960 B, linear [pr][col][g][ci8]
    __shared__ int rmap[32], cmap[20];

    const int tid  = threadIdx.x;
    const int orig = blockIdx.x;                  // 1152 blocks = 8 XCD * 144
    const int b    = orig & 7;                    // XCD-bijective: image b per XCD
    const int idx  = orig >> 3;                   // 0..143
    const int rt   = idx >> 4;                    // 0..8
    const int ct   = idx & 15;                    // 0..15
    const int i0 = rt * 28, j0 = ct * 16;

    // reflect+circular maps: padded coord (base+1+k) mod 256, then reflect(-2)
    if (tid < 52) {
        int k    = tid < 32 ? tid : tid - 32;
        int base = tid < 32 ? i0  : j0;
        int r = (base + 1 + k) & 255;
        int t = r - 2;
        int m = t < 0 ? -t : (t > 251 ? 502 - t : t);
        if (tid < 32) rmap[k] = m; else cmap[k] = m;
    }
    __syncthreads();

    // ---- stage patch: 2560 tasks, exactly 10 per thread ----
    {
        const float* xb = x + (size_t)b * NCH * PLANE;
        #pragma unroll
        for (int it = 0; it < 10; ++it) {
            int task = it * 256 + tid;
            int g    = task & 3;
            int pc   = task >> 2;          // pr*20 + col
            int pr   = pc / 20;
            int col  = pc - pr * 20;
            const float* src = xb + (size_t)(g * 8) * PLANE
                                  + (size_t)rmap[pr] * HW_ + cmap[col];
            unsigned short pk[8];
            #pragma unroll
            for (int q = 0; q < 8; ++q)
                pk[q] = __builtin_bit_cast(unsigned short,
                            __float2bfloat16(src[q * PLANE]));
            *reinterpret_cast<uint4*>(reinterpret_cast<char*>(xl) + task * 16)
                = *reinterpret_cast<const uint4*>(pk);
        }
    }
    __syncthreads();

    const int lane = tid & 63;
    const int wid  = tid >> 6;
    const int lm   = lane & 15;    // o-within-16 (A) / pixel col (B,D)
    const int lg   = lane >> 4;    // k-group
    const int rowb = wid * 7;      // wave's first local output row

    const char* xlb = reinterpret_cast<const char*>(xl);
    const char* wb  = reinterpret_cast<const char*>(wp);
    const int afix  = (lm << 6) + (lg << 4);
    const int j     = j0 + lm;

    f32x4 acc[7][2];
    #pragma unroll
    for (int r = 0; r < 7; ++r) {
        acc[r][0] = (f32x4){0.f, 0.f, 0.f, 0.f};
        acc[r][1] = (f32x4){0.f, 0.f, 0.f, 0.f};
    }

    #pragma unroll
    for (int db = 0; db < 5; ++db) {
        bf16x8 a[5][2];
        #pragma unroll
        for (int da = 0; da < 5; ++da) {
            const char* ap = wb + ((da * 5 + db) << 11) + afix;
            a[da][0] = *reinterpret_cast<const bf16x8*>(ap);
            a[da][1] = *reinterpret_cast<const bf16x8*>(ap + 1024);
        }

        #pragma unroll
        for (int l = 0; l < 11; ++l) {
            // patch row rowb+l, cols lm+db: contiguous 1KB per wave, conflict-free
            bf16x8 bf = *reinterpret_cast<const bf16x8*>(
                xlb + (rowb + l) * 1280 + ((lm + db) << 6) + (lg << 4));
            #pragma unroll
            for (int da = 0; da < 5; ++da) {
                const int r = l - da;
                if (r >= 0 && r < 7) {
                    acc[r][0] = __builtin_amdgcn_mfma_f32_16x16x32_bf16(
                        a[da][0], bf, acc[r][0], 0, 0, 0);
                    acc[r][1] = __builtin_amdgcn_mfma_f32_16x16x32_bf16(
                        a[da][1], bf, acc[r][1], 0, 0, 0);
                }
            }
        }
    }

    // store: o = mt*16 + lg*4 + q, col = lm (rows always in-bounds; 252=9*28)
    #pragma unroll
    for (int r = 0; r < 7; ++r) {
        const int i = i0 + rowb + r;
        if (j < HW_) {
            #pragma unroll
            for (int mt = 0; mt < 2; ++mt) {
                size_t rowoff = ((size_t)(b * NCH + mt * 16 + lg * 4)) * PLANE
                              + (size_t)i * HW_ + j;
                #pragma unroll
                for (int q = 0; q < 4; ++q)
                    out[rowoff + (size_t)q * PLANE] = acc[r][mt][q];
            }
        }
    }
}

// ---------------- fallback (ws too small): R2-style single kernel ----------------
__global__ __launch_bounds__(256) void conv_mfma_fb(
    const float* __restrict__ x,
    const float* __restrict__ w_raw,
    float* __restrict__ out)
{
    __shared__ unsigned short xl[12800];
    __shared__ unsigned short wl[25600];
    __shared__ int rmap[20], cmap[20];

    const int tid = threadIdx.x;
    const int bid = blockIdx.x;
    const int b  = bid >> 8;
    const int rt = (bid >> 4) & 15;
    const int ct = bid & 15;
    const int i0 = rt * 16, j0 = ct * 16;

    if (tid < 40) {
        int k    = tid < 20 ? tid : tid - 20;
        int base = tid < 20 ? i0  : j0;
        int r = (base + 1 + k) & 255;
        int t = r - 2;
        int m = t < 0 ? -t : (t > 251 ? 502 - t : t);
        if (tid < 20) rmap[k] = m; else cmap[k] = m;
    }
    for (int e = tid; e < 25600; e += 256) {
        int o   = e / 800;
        int rem = e - o * 800;
        int ci  = rem / 25;
        int kd  = rem - ci * 25;
        wl[(24 - kd) * 1024 + o * 32 + ci] = f2bf(w_raw[e]);
    }
    __syncthreads();

    for (int task = tid; task < 1600; task += 256) {
        int col = task % 20;
        int g   = (task / 20) & 3;
        int row = task / 80;
        const float* src = x + (size_t)(b * NCH + g * 8) * PLANE
                             + (size_t)rmap[row] * HW_ + cmap[col];
        unsigned short pk[8];
        #pragma unroll
        for (int q = 0; q < 8; ++q) pk[q] = f2bf(src[q * PLANE]);
        int off = ((row * 20 + col) << 6) + ((g ^ (col & 3)) << 4);
        *reinterpret_cast<uint4*>(reinterpret_cast<char*>(xl) + off)
            = *reinterpret_cast<const uint4*>(pk);
    }
    __syncthreads();

    const int lane  = tid & 63;
    const int wid   = tid >> 6;
    const int lm    = lane & 15;
    const int lg    = lane >> 4;
    const int rbase = wid * 4;

    f32x4 acc[4][2];
    #pragma unroll
    for (int rr = 0; rr < 4; ++rr) {
        acc[rr][0] = (f32x4){0.f, 0.f, 0.f, 0.f};
        acc[rr][1] = (f32x4){0.f, 0.f, 0.f, 0.f};
    }

    const char* wbase = (const char*)wl;
    const int afix = (lm << 6) + (lg << 4);
    const char* xlb = reinterpret_cast<const char*>(xl);

    #pragma unroll
    for (int da = 0; da < 5; ++da) {
        #pragma unroll
        for (int db = 0; db < 5; ++db) {
            const int t = da * 5 + db;
            bf16x8 a0 = *reinterpret_cast<const bf16x8*>(wbase + (t << 11) + afix);
            bf16x8 a1 = *reinterpret_cast<const bf16x8*>(wbase + (t << 11) + 1024 + afix);
            const int col  = lm + db;
            const int coff = (col << 6) + ((lg ^ (col & 3)) << 4);
            #pragma unroll
            for (int rr = 0; rr < 4; ++rr) {
                const int row = rbase + rr + da;
                bf16x8 bf = *reinterpret_cast<const bf16x8*>(xlb + row * 1280 + coff);
                acc[rr][0] = __builtin_amdgcn_mfma_f32_16x16x32_bf16(a0, bf, acc[rr][0], 0, 0, 0);
                acc[rr][1] = __builtin_amdgcn_mfma_f32_16x16x32_bf16(a1, bf, acc[rr][1], 0, 0, 0);
            }
        }
    }

    const int j = j0 + lm;
    #pragma unroll
    for (int rr = 0; rr < 4; ++rr) {
        const int i = i0 + rbase + rr;
        if (i < HW_ && j < HW_) {
            size_t rowoff = (size_t)(b * NCH) * PLANE + (size_t)i * HW_ + j;
            #pragma unroll
            for (int mt = 0; mt < 2; ++mt)
                #pragma unroll
                for (int q = 0; q < 4; ++q) {
                    int o = mt * 16 + lg * 4 + q;
                    out[rowoff + (size_t)o * PLANE] = acc[rr][mt][q];
                }
        }
    }
}

extern "C" void kernel_launch(void* const* d_in, const int* in_sizes, int n_in,
                              void* d_out, int out_size, void* d_ws, size_t ws_size,
                              hipStream_t stream) {
    const float* x = (const float*)d_in[0];
    const float* w = (const float*)d_in[1];
    float* out = (float*)d_out;

    if (ws_size >= WS_NEED) {
        unsigned short* wp = (unsigned short*)d_ws;
        hipLaunchKernelGGL(pack_w_kernel, dim3(100), dim3(256), 0, stream, w, wp);
        hipLaunchKernelGGL(conv_fused, dim3(1152), dim3(256), 0, stream,
                           x, (const unsigned short*)wp, out);
    } else {
        hipLaunchKernelGGL(conv_mfma_fb, dim3(2048), dim3(256), 0, stream, x, w, out);
    }
}